// Round 1
// baseline (1354.994 us; speedup 1.0000x reference)
//
#include <hip/hip_runtime.h>

#define NB 4
#define SEQ 1024
#define DM 1024
#define NH 16
#define DEP 64
#define DFFN 4096

typedef __attribute__((ext_vector_type(8))) short short8;
typedef __attribute__((ext_vector_type(4))) float f32x4;
typedef __attribute__((ext_vector_type(4))) unsigned short us4;

__device__ __forceinline__ unsigned short f2bf(float f) {
    union { float f; unsigned int u; } v; v.f = f;
    unsigned int u = v.u;
    return (unsigned short)((u + 0x7FFFu + ((u >> 16) & 1u)) >> 16);
}

// ---------------- cast f32 -> bf16 (vectorized) ----------------
__global__ __launch_bounds__(256) void cast_bf16_kernel(const float* __restrict__ in,
                                                        unsigned short* __restrict__ out, int n4) {
    int i = blockIdx.x * 256 + threadIdx.x;
    if (i < n4) {
        float4 f = ((const float4*)in)[i];
        us4 u;
        u[0] = f2bf(f.x); u[1] = f2bf(f.y); u[2] = f2bf(f.z); u[3] = f2bf(f.w);
        ((us4*)out)[i] = u;
    }
}

// ---------------- generic bf16 GEMM: C = A(MxK) @ W(KxN) + bias ----------------
// 128x128 tile, BK=32, 4 waves (2x2 of 64x64), mfma_f32_16x16x32_bf16
template <int RELU, int WB, int WF>
__global__ __launch_bounds__(256) void gemm_kernel(const unsigned short* __restrict__ A,
                                                   const unsigned short* __restrict__ W,
                                                   const float* __restrict__ bias,
                                                   unsigned short* __restrict__ Cb,
                                                   float* __restrict__ Cf,
                                                   int M, int N, int K) {
    __shared__ unsigned short As[128][40];
    __shared__ unsigned short Bs[128][40];  // transposed: Bs[n][k]
    const int t = threadIdx.x;
    const int lane = t & 63, w = t >> 6;
    const int m0 = blockIdx.y * 128, n0 = blockIdx.x * 128;
    const int wm = (w >> 1) * 64, wn = (w & 1) * 64;
    const int lr = lane & 15, kb = (lane >> 4) * 8;

    f32x4 acc[4][4];
#pragma unroll
    for (int a = 0; a < 4; ++a)
#pragma unroll
        for (int b = 0; b < 4; ++b)
#pragma unroll
            for (int j = 0; j < 4; ++j) acc[a][b][j] = 0.f;

    for (int kt = 0; kt < K; kt += 32) {
        __syncthreads();
        // stage A tile 128x32
#pragma unroll
        for (int p = 0; p < 2; ++p) {
            int idx = p * 256 + t;
            int r = idx >> 2, c8 = (idx & 3) * 8;
            short8 v = *(const short8*)(A + (size_t)(m0 + r) * K + kt + c8);
            *(short8*)&As[r][c8] = v;
        }
        // stage W tile 32x128, transposed into Bs[n][k]
#pragma unroll
        for (int p = 0; p < 2; ++p) {
            int idx = p * 256 + t;
            int kk = idx >> 4, nn8 = (idx & 15) * 8;
            short8 v = *(const short8*)(W + (size_t)(kt + kk) * N + n0 + nn8);
#pragma unroll
            for (int j = 0; j < 8; ++j) Bs[nn8 + j][kk] = (unsigned short)v[j];
        }
        __syncthreads();

        short8 af[4], bfr[4];
#pragma unroll
        for (int i = 0; i < 4; ++i) af[i] = *(const short8*)&As[wm + i * 16 + lr][kb];
#pragma unroll
        for (int i = 0; i < 4; ++i) bfr[i] = *(const short8*)&Bs[wn + i * 16 + lr][kb];
#pragma unroll
        for (int am = 0; am < 4; ++am)
#pragma unroll
            for (int bn = 0; bn < 4; ++bn)
                acc[am][bn] = __builtin_amdgcn_mfma_f32_16x16x32_bf16(af[am], bfr[bn], acc[am][bn], 0, 0, 0);
    }

#pragma unroll
    for (int am = 0; am < 4; ++am) {
#pragma unroll
        for (int bn = 0; bn < 4; ++bn) {
            int col = n0 + wn + bn * 16 + lr;
            float bv = bias ? bias[col] : 0.f;
#pragma unroll
            for (int i = 0; i < 4; ++i) {
                int row = m0 + wm + am * 16 + (lane >> 4) * 4 + i;
                float v = acc[am][bn][i] + bv;
                if (RELU) v = v > 0.f ? v : 0.f;
                if (WF) Cf[(size_t)row * N + col] = v;
                if (WB) Cb[(size_t)row * N + col] = f2bf(v);
            }
        }
    }
}

// ---------------- QK^T: logits = Q.Kt/8 + masks, per (b,h) ----------------
// grid: (SK/128, SQ/128, B*NH)
template <int CAUSAL>
__global__ __launch_bounds__(256) void qk_kernel(const unsigned short* __restrict__ Q,
                                                 const unsigned short* __restrict__ Km,
                                                 const float* __restrict__ pad,  // (B,SK) or null
                                                 float* __restrict__ out) {
    __shared__ unsigned short Qs[128][72];
    __shared__ unsigned short Ks[128][72];
    const int t = threadIdx.x, lane = t & 63, w = t >> 6;
    const int q0 = blockIdx.y * 128, k0 = blockIdx.x * 128;
    const int b = blockIdx.z >> 4, h = blockIdx.z & 15;
    const size_t qbase = ((size_t)b * SEQ) * DM + h * DEP;

#pragma unroll
    for (int p = 0; p < 4; ++p) {
        int idx = p * 256 + t;
        int r = idx >> 3, c8 = (idx & 7) * 8;
        *(short8*)&Qs[r][c8] = *(const short8*)(Q + qbase + (size_t)(q0 + r) * DM + c8);
        *(short8*)&Ks[r][c8] = *(const short8*)(Km + qbase + (size_t)(k0 + r) * DM + c8);
    }
    __syncthreads();

    const int wm = (w >> 1) * 64, wn = (w & 1) * 64;
    const int lr = lane & 15, kb = (lane >> 4) * 8;
    f32x4 acc[4][4];
#pragma unroll
    for (int a = 0; a < 4; ++a)
#pragma unroll
        for (int b2 = 0; b2 < 4; ++b2)
#pragma unroll
            for (int j = 0; j < 4; ++j) acc[a][b2][j] = 0.f;

#pragma unroll
    for (int ks = 0; ks < 64; ks += 32) {
        short8 af[4], bfr[4];
#pragma unroll
        for (int i = 0; i < 4; ++i) af[i] = *(const short8*)&Qs[wm + i * 16 + lr][ks + kb];
#pragma unroll
        for (int i = 0; i < 4; ++i) bfr[i] = *(const short8*)&Ks[wn + i * 16 + lr][ks + kb];
#pragma unroll
        for (int am = 0; am < 4; ++am)
#pragma unroll
            for (int bn = 0; bn < 4; ++bn)
                acc[am][bn] = __builtin_amdgcn_mfma_f32_16x16x32_bf16(af[am], bfr[bn], acc[am][bn], 0, 0, 0);
    }

#pragma unroll
    for (int am = 0; am < 4; ++am) {
#pragma unroll
        for (int bn = 0; bn < 4; ++bn) {
            int gk = k0 + wn + bn * 16 + lr;
            float pm = pad ? pad[(size_t)b * SEQ + gk] * -1e9f : 0.f;
#pragma unroll
            for (int i = 0; i < 4; ++i) {
                int gq = q0 + wm + am * 16 + (lane >> 4) * 4 + i;
                float v = acc[am][bn][i] * 0.125f + pm;
                if (CAUSAL && gk > gq) v -= 1e9f;
                out[((size_t)blockIdx.z * SEQ + gq) * SEQ + gk] = v;
            }
        }
    }
}

// ---------------- row softmax in-place, row length 1024 ----------------
__global__ __launch_bounds__(256) void softmax_kernel(float* __restrict__ P) {
    size_t row = blockIdx.x;
    float* p = P + (row << 10);
    const int t = threadIdx.x;
    float4 v = ((float4*)p)[t];
    float m = fmaxf(fmaxf(v.x, v.y), fmaxf(v.z, v.w));
#pragma unroll
    for (int off = 32; off; off >>= 1) m = fmaxf(m, __shfl_down(m, off));
    __shared__ float rmax[4], rsum[4];
    if ((t & 63) == 0) rmax[t >> 6] = m;
    __syncthreads();
    m = fmaxf(fmaxf(rmax[0], rmax[1]), fmaxf(rmax[2], rmax[3]));
    v.x = __expf(v.x - m); v.y = __expf(v.y - m);
    v.z = __expf(v.z - m); v.w = __expf(v.w - m);
    float s = v.x + v.y + v.z + v.w;
#pragma unroll
    for (int off = 32; off; off >>= 1) s += __shfl_down(s, off);
    if ((t & 63) == 0) rsum[t >> 6] = s;
    __syncthreads();
    s = rsum[0] + rsum[1] + rsum[2] + rsum[3];
    float inv = 1.0f / s;
    v.x *= inv; v.y *= inv; v.z *= inv; v.w *= inv;
    ((float4*)p)[t] = v;
}

// ---------------- PV: ctx = P(f32) @ V, per (b,h) ----------------
// grid: (SQ/128, B*NH); ctx written as (B,SQ,H*DEP)
__global__ __launch_bounds__(256) void pv_kernel(const float* __restrict__ P,
                                                 const unsigned short* __restrict__ V,
                                                 unsigned short* __restrict__ ctx) {
    __shared__ unsigned short Ps[128][40];
    __shared__ unsigned short Vs[64][40];  // Vs[dep][k]
    const int t = threadIdx.x, lane = t & 63, w = t >> 6;
    const int q0 = blockIdx.x * 128;
    const int b = blockIdx.y >> 4, h = blockIdx.y & 15;
    const float* Pb = P + ((size_t)blockIdx.y << 20);
    const unsigned short* Vb = V + ((size_t)b * SEQ) * DM + h * DEP;
    const int wm = w * 32, lr = lane & 15, kb = (lane >> 4) * 8;

    f32x4 acc[2][4];
#pragma unroll
    for (int a = 0; a < 2; ++a)
#pragma unroll
        for (int b2 = 0; b2 < 4; ++b2)
#pragma unroll
            for (int j = 0; j < 4; ++j) acc[a][b2][j] = 0.f;

    for (int kt = 0; kt < SEQ; kt += 32) {
        __syncthreads();
        // stage P 128x32 (f32 -> bf16)
#pragma unroll
        for (int p = 0; p < 4; ++p) {
            int id = p * 256 + t;
            int r = id >> 3, c4 = (id & 7) * 4;
            float4 f = *(const float4*)(Pb + (size_t)(q0 + r) * SEQ + kt + c4);
            us4 u;
            u[0] = f2bf(f.x); u[1] = f2bf(f.y); u[2] = f2bf(f.z); u[3] = f2bf(f.w);
            *(us4*)&Ps[r][c4] = u;
        }
        // stage V 32x64 transposed -> Vs[dep][k]
        {
            int r = t >> 3, c8 = (t & 7) * 8;
            short8 v = *(const short8*)(Vb + (size_t)(kt + r) * DM + c8);
#pragma unroll
            for (int j = 0; j < 8; ++j) Vs[c8 + j][r] = (unsigned short)v[j];
        }
        __syncthreads();

        short8 af[2], bfr[4];
#pragma unroll
        for (int i = 0; i < 2; ++i) af[i] = *(const short8*)&Ps[wm + i * 16 + lr][kb];
#pragma unroll
        for (int i = 0; i < 4; ++i) bfr[i] = *(const short8*)&Vs[i * 16 + lr][kb];
#pragma unroll
        for (int am = 0; am < 2; ++am)
#pragma unroll
            for (int bn = 0; bn < 4; ++bn)
                acc[am][bn] = __builtin_amdgcn_mfma_f32_16x16x32_bf16(af[am], bfr[bn], acc[am][bn], 0, 0, 0);
    }

#pragma unroll
    for (int am = 0; am < 2; ++am) {
#pragma unroll
        for (int bn = 0; bn < 4; ++bn) {
            int dep = bn * 16 + lr;
#pragma unroll
            for (int i = 0; i < 4; ++i) {
                int gq = q0 + wm + am * 16 + (lane >> 4) * 4 + i;
                ctx[((size_t)b * SEQ + gq) * DM + h * DEP + dep] = f2bf(acc[am][bn][i]);
            }
        }
    }
}

// ---------------- residual + layernorm: out = LN(X + R) ----------------
template <int WB>
__global__ __launch_bounds__(256) void ln_kernel(const float* __restrict__ X,
                                                 const float* __restrict__ R,
                                                 const float* __restrict__ gamma,
                                                 const float* __restrict__ beta,
                                                 float* __restrict__ outF,
                                                 unsigned short* __restrict__ outB) {
    size_t row = blockIdx.x;
    const int t = threadIdx.x;
    float4 a = ((const float4*)(X + (row << 10)))[t];
    float4 r = ((const float4*)(R + (row << 10)))[t];
    float v0 = a.x + r.x, v1 = a.y + r.y, v2 = a.z + r.z, v3 = a.w + r.w;
    float s = v0 + v1 + v2 + v3;
    float q = v0 * v0 + v1 * v1 + v2 * v2 + v3 * v3;
#pragma unroll
    for (int off = 32; off; off >>= 1) {
        s += __shfl_down(s, off);
        q += __shfl_down(q, off);
    }
    __shared__ float rs[4], rq[4];
    if ((t & 63) == 0) { rs[t >> 6] = s; rq[t >> 6] = q; }
    __syncthreads();
    s = rs[0] + rs[1] + rs[2] + rs[3];
    q = rq[0] + rq[1] + rq[2] + rq[3];
    float mean = s * (1.0f / 1024.0f);
    float var = q * (1.0f / 1024.0f) - mean * mean;
    float inv = rsqrtf(var + 1e-6f);
    float g0 = gamma[t * 4], g1 = gamma[t * 4 + 1], g2 = gamma[t * 4 + 2], g3 = gamma[t * 4 + 3];
    float b0 = beta[t * 4], b1 = beta[t * 4 + 1], b2 = beta[t * 4 + 2], b3 = beta[t * 4 + 3];
    float o0 = (v0 - mean) * inv * g0 + b0;
    float o1 = (v1 - mean) * inv * g1 + b1;
    float o2 = (v2 - mean) * inv * g2 + b2;
    float o3 = (v3 - mean) * inv * g3 + b3;
    float4 o; o.x = o0; o.y = o1; o.z = o2; o.w = o3;
    ((float4*)(outF + (row << 10)))[t] = o;
    if (WB) {
        us4 u;
        u[0] = f2bf(o0); u[1] = f2bf(o1); u[2] = f2bf(o2); u[3] = f2bf(o3);
        ((us4*)(outB + (row << 10)))[t] = u;
    }
}

extern "C" void kernel_launch(void* const* d_in, const int* in_sizes, int n_in,
                              void* d_out, int out_size, void* d_ws, size_t ws_size,
                              hipStream_t stream) {
    const float* x = (const float*)d_in[0];
    const float* enc = (const float*)d_in[1];
    const float* pad = (const float*)d_in[3];
    const float* wq1 = (const float*)d_in[4];  const float* bq1 = (const float*)d_in[5];
    const float* wk1 = (const float*)d_in[6];  const float* bk1 = (const float*)d_in[7];
    const float* wv1 = (const float*)d_in[8];  const float* bv1 = (const float*)d_in[9];
    const float* wo1 = (const float*)d_in[10]; const float* bo1 = (const float*)d_in[11];
    const float* wq2 = (const float*)d_in[12]; const float* bq2 = (const float*)d_in[13];
    const float* wk2 = (const float*)d_in[14]; const float* bk2 = (const float*)d_in[15];
    const float* wv2 = (const float*)d_in[16]; const float* bv2 = (const float*)d_in[17];
    const float* wo2 = (const float*)d_in[18]; const float* bo2 = (const float*)d_in[19];
    const float* wf1 = (const float*)d_in[20]; const float* bf1 = (const float*)d_in[21];
    const float* wf2 = (const float*)d_in[22]; const float* bf2 = (const float*)d_in[23];
    const float* g1 = (const float*)d_in[24]; const float* be1 = (const float*)d_in[25];
    const float* g2 = (const float*)d_in[26]; const float* be2 = (const float*)d_in[27];
    const float* g3 = (const float*)d_in[28]; const float* be3 = (const float*)d_in[29];

    float* out3 = (float*)d_out;
    float* aw1 = out3 + (size_t)NB * SEQ * DM;
    float* aw2 = aw1 + (size_t)NB * NH * SEQ * SEQ;

    // ----- workspace arena -----
    char* ws = (char*)d_ws;
    size_t off = 0;
    auto take = [&](size_t n) { char* p = ws + off; off += (n + 255) & ~(size_t)255; return p; };
    const size_t SZ_DD_BF = (size_t)DM * DM * 2;          // 2 MB
    const size_t SZ_SD_BF = (size_t)NB * SEQ * DM * 2;    // 8 MB
    const size_t SZ_SD_F  = (size_t)NB * SEQ * DM * 4;    // 16 MB

    unsigned short* wq1b = (unsigned short*)take(SZ_DD_BF);
    unsigned short* wk1b = (unsigned short*)take(SZ_DD_BF);
    unsigned short* wv1b = (unsigned short*)take(SZ_DD_BF);
    unsigned short* wo1b = (unsigned short*)take(SZ_DD_BF);
    unsigned short* wq2b = (unsigned short*)take(SZ_DD_BF);
    unsigned short* wk2b = (unsigned short*)take(SZ_DD_BF);
    unsigned short* wv2b = (unsigned short*)take(SZ_DD_BF);
    unsigned short* wo2b = (unsigned short*)take(SZ_DD_BF);
    unsigned short* wf1b = (unsigned short*)take((size_t)DM * DFFN * 2);
    unsigned short* wf2b = (unsigned short*)take((size_t)DFFN * DM * 2);
    unsigned short* xb   = (unsigned short*)take(SZ_SD_BF);
    unsigned short* encb = (unsigned short*)take(SZ_SD_BF);
    unsigned short* qb   = (unsigned short*)take(SZ_SD_BF);
    unsigned short* kb_  = (unsigned short*)take(SZ_SD_BF);
    unsigned short* vb   = (unsigned short*)take(SZ_SD_BF);
    unsigned short* ctx  = (unsigned short*)take(SZ_SD_BF);
    float* goutf = (float*)take(SZ_SD_F);
    float* out1f = (float*)take(SZ_SD_F);
    unsigned short* out1b = (unsigned short*)take(SZ_SD_BF);
    float* out2f = (float*)take(SZ_SD_F);
    unsigned short* out2b = (unsigned short*)take(SZ_SD_BF);
    unsigned short* ffn1b = (unsigned short*)take((size_t)NB * SEQ * DFFN * 2);

    auto cast = [&](const float* src, unsigned short* dst, size_t n) {
        cast_bf16_kernel<<<(unsigned)((n / 4 + 255) / 256), 256, 0, stream>>>(src, dst, (int)(n / 4));
    };
    cast(x, xb, (size_t)NB * SEQ * DM);
    cast(enc, encb, (size_t)NB * SEQ * DM);
    cast(wq1, wq1b, (size_t)DM * DM); cast(wk1, wk1b, (size_t)DM * DM);
    cast(wv1, wv1b, (size_t)DM * DM); cast(wo1, wo1b, (size_t)DM * DM);
    cast(wq2, wq2b, (size_t)DM * DM); cast(wk2, wk2b, (size_t)DM * DM);
    cast(wv2, wv2b, (size_t)DM * DM); cast(wo2, wo2b, (size_t)DM * DM);
    cast(wf1, wf1b, (size_t)DM * DFFN); cast(wf2, wf2b, (size_t)DFFN * DM);

    const int M = NB * SEQ;  // 4096
    dim3 gDD(DM / 128, M / 128);     // N=1024
    dim3 gDF(DFFN / 128, M / 128);   // N=4096
    dim3 gQK(SEQ / 128, SEQ / 128, NB * NH);
    dim3 gPV(SEQ / 128, NB * NH);

    // ---- MHA1 (self, causal) ----
    gemm_kernel<0, 1, 0><<<gDD, 256, 0, stream>>>(xb, wq1b, bq1, qb, nullptr, M, DM, DM);
    gemm_kernel<0, 1, 0><<<gDD, 256, 0, stream>>>(xb, wk1b, bk1, kb_, nullptr, M, DM, DM);
    gemm_kernel<0, 1, 0><<<gDD, 256, 0, stream>>>(xb, wv1b, bv1, vb, nullptr, M, DM, DM);
    qk_kernel<1><<<gQK, 256, 0, stream>>>(qb, kb_, nullptr, aw1);
    softmax_kernel<<<NB * NH * SEQ, 256, 0, stream>>>(aw1);
    pv_kernel<<<gPV, 256, 0, stream>>>(aw1, vb, ctx);
    gemm_kernel<0, 0, 1><<<gDD, 256, 0, stream>>>(ctx, wo1b, bo1, nullptr, goutf, M, DM, DM);
    ln_kernel<1><<<M, 256, 0, stream>>>(goutf, x, g1, be1, out1f, out1b);

    // ---- MHA2 (cross, padding mask) ----
    gemm_kernel<0, 1, 0><<<gDD, 256, 0, stream>>>(out1b, wq2b, bq2, qb, nullptr, M, DM, DM);
    gemm_kernel<0, 1, 0><<<gDD, 256, 0, stream>>>(encb, wk2b, bk2, kb_, nullptr, M, DM, DM);
    gemm_kernel<0, 1, 0><<<gDD, 256, 0, stream>>>(encb, wv2b, bv2, vb, nullptr, M, DM, DM);
    qk_kernel<0><<<gQK, 256, 0, stream>>>(qb, kb_, pad, aw2);
    softmax_kernel<<<NB * NH * SEQ, 256, 0, stream>>>(aw2);
    pv_kernel<<<gPV, 256, 0, stream>>>(aw2, vb, ctx);
    gemm_kernel<0, 0, 1><<<gDD, 256, 0, stream>>>(ctx, wo2b, bo2, nullptr, goutf, M, DM, DM);
    ln_kernel<1><<<M, 256, 0, stream>>>(goutf, out1f, g2, be2, out2f, out2b);

    // ---- FFN ----
    gemm_kernel<1, 1, 0><<<gDF, 256, 0, stream>>>(out2b, wf1b, bf1, ffn1b, nullptr, M, DFFN, DM);
    gemm_kernel<0, 0, 1><<<gDD, 256, 0, stream>>>(ffn1b, wf2b, bf2, nullptr, goutf, M, DM, DFFN);
    ln_kernel<0><<<M, 256, 0, stream>>>(goutf, out2f, g3, be3, out3, nullptr);
}